// Round 14
// baseline (1249.013 us; speedup 1.0000x reference)
//
#include <hip/hip_runtime.h>
#include <math.h>

#define NB   8
#define NPTS 4096
#define MPER 1024
#define MTOT (NB*MPER)
#define CIN  64
#define KNN  64
// (0.2*0.2) computed in double, as the reference's python-float R*R
#define R2D  0.04000000000000001

typedef unsigned int u32;
typedef unsigned long long u64;
typedef float v2f __attribute__((ext_vector_type(2)));
using s16x8 = __attribute__((ext_vector_type(8))) short;   // 8 bf16 (4 VGPRs)
using f32x4 = __attribute__((ext_vector_type(4))) float;

// exact IEEE fp32 distance, reference order: ((dx*dx + dy*dy) + dz*dz), no FMA
__device__ __forceinline__ float d2f(float ax, float ay, float az,
                                     float bx, float by, float bz) {
    float dx = __fsub_rn(ax, bx);
    float dy = __fsub_rn(ay, by);
    float dz = __fsub_rn(az, bz);
    return __fadd_rn(__fadd_rn(__fmul_rn(dx, dx), __fmul_rn(dy, dy)),
                     __fmul_rn(dz, dz));
}

// CDNA packed 2xFP32 ops — IEEE-identical per component; asm, never contracted.
__device__ __forceinline__ v2f pk_add(v2f a, v2f b) {
    v2f d;
    asm("v_pk_add_f32 %0, %1, %2" : "=v"(d) : "v"(a), "v"(b));
    return d;
}
__device__ __forceinline__ v2f pk_mul(v2f a, v2f b) {
    v2f d;
    asm("v_pk_mul_f32 %0, %1, %2" : "=v"(d) : "v"(a), "v"(b));
    return d;
}

// float -> bf16 bits, round-to-nearest-even (finite inputs only)
__device__ __forceinline__ unsigned short f2bf(float f) {
    u32 x = __float_as_uint(f);
    u32 r = (x + 0x7fffu + ((x >> 16) & 1u)) >> 16;
    return (unsigned short)r;
}
__device__ __forceinline__ u32 pk2(float a, float b) {
    return (u32)f2bf(a) | ((u32)f2bf(b) << 16);
}

__device__ __forceinline__ f32x4 mfma16(s16x8 a, s16x8 b, f32x4 c) {
    return __builtin_amdgcn_mfma_f32_16x16x32_bf16(a, b, c, 0, 0, 0);
}

// full-wave (64-lane) max reduction of a u64 key via DPP; result valid in lane 63.
__device__ __forceinline__ u64 wave_max_u64_dpp(u64 key)
{
#define DPPMAX(ctrl, rmask) do {                                                   \
        u32 lo_ = (u32)key;                                                        \
        u32 hi_ = (u32)(key >> 32);                                                \
        u32 plo = (u32)__builtin_amdgcn_update_dpp(                                \
            0, (int)lo_, ctrl, rmask, 0xf, false);                                 \
        u32 phi = (u32)__builtin_amdgcn_update_dpp(                                \
            0, (int)hi_, ctrl, rmask, 0xf, false);                                 \
        u64 pk = ((u64)phi << 32) | plo;                                           \
        if (pk > key) key = pk;                                                    \
    } while (0)
    DPPMAX(0x111, 0xf);   // row_shr:1
    DPPMAX(0x112, 0xf);   // row_shr:2
    DPPMAX(0x114, 0xf);   // row_shr:4
    DPPMAX(0x118, 0xf);   // row_shr:8
    DPPMAX(0x142, 0xa);   // row_bcast:15 -> rows 1,3
    DPPMAX(0x143, 0xc);   // row_bcast:31 -> rows 2,3
#undef DPPMAX
    return key;
}

// ---------------- prep: bf16 weights (blk 0-79) + sel=-1 (blk 80-111) + wq ----
#define W1T_U 6656
#define W2T_U 4608
#define W3T_U 9216
#define WTOT_U 20480

__global__ __launch_bounds__(256) void prep_weights(
    const float* __restrict__ W1, const float* __restrict__ W2,
    const float* __restrict__ W3, unsigned short* __restrict__ wsW,
    int* __restrict__ sel, int* __restrict__ wq)
{
    const int bid = blockIdx.x;
    const int t = threadIdx.x;
    if (bid >= 112) {                     // wq init
        if (t == 0) *wq = 0;
        return;
    }
    if (bid >= 80) {                      // sel sentinel init (-1: unpublished)
        sel[(bid - 80) * 256 + t] = -1;
        return;
    }
    int i = bid * 256 + t;
    float v;
    if (i < W1T_U) {
        int cr = i / 104, k = i - cr * 104;
        v = (k < 67) ? W1[k * 64 + cr] : 0.0f;
    } else if (i < W1T_U + W2T_U) {
        int j = i - W1T_U;
        int cr = j / 72, k = j - cr * 72;
        v = (k < 64) ? W2[k * 64 + cr] : 0.0f;
    } else {
        int j = i - (W1T_U + W2T_U);
        int cr = j / 72, k = j - cr * 72;
        v = (k < 64) ? W3[k * 128 + cr] : 0.0f;
    }
    wsW[i] = f2bf(v);
}

// ================= fused kernel: 8 FPS blocks + 120 persistent workers =========
// r12 structure verbatim; ONE knob changed: grid 256 -> 128. Half the chip
// stays dark -> higher sustained clock for the latency-bound FPS blocks, and
// half the coherent-point poll/ack pressure. Worker capacity 120 x (600us /
// ~5.5us per slot) ~ 13k slots > 8192, so consumption still keeps up with
// publication (no tail growth); FPS blocks join the pool when done.

// ---- FPS producer (r7-proven compute structure) ----
__device__ __forceinline__ void fps_body(char* smem, const float* __restrict__ pos,
                                         int* __restrict__ sel)
{
    const int b    = blockIdx.x;
    const int t    = threadIdx.x;
    const int lane = t & 63;
    const int wv   = t >> 6;
    const float* pb = pos + (size_t)b * NPTS * 3;

    float4* lp = (float4*)smem;              // 64 KB
    u64*    part = (u64*)(smem + 65536);     // [2][4]

    v2f px[8], py[8], pz[8], mind[8];
#pragma unroll
    for (int pr = 0; pr < 8; ++pr) {
        int j0 = (2 * pr + 0) * 256 + t;
        int j1 = (2 * pr + 1) * 256 + t;
        float x0 = pb[j0 * 3 + 0], y0 = pb[j0 * 3 + 1], z0 = pb[j0 * 3 + 2];
        float x1 = pb[j1 * 3 + 0], y1 = pb[j1 * 3 + 1], z1 = pb[j1 * 3 + 2];
        px[pr] = v2f{x0, x1}; py[pr] = v2f{y0, y1}; pz[pr] = v2f{z0, z1};
        mind[pr] = v2f{3.0e38f, 3.0e38f};
        lp[j0] = float4{x0, y0, z0, 0.f};
        lp[j1] = float4{x1, y1, z1, 0.f};
    }
    __syncthreads();

    float4 c0 = lp[0];
    float cx = c0.x, cy = c0.y, cz = c0.z;
    int mypick = 0;                          // t==0 carries slot-0 pick (idx 0)

    for (int it = 1; it < MPER; ++it) {
        const v2f ncx = v2f{-cx, -cx};
        const v2f ncy = v2f{-cy, -cy};
        const v2f ncz = v2f{-cz, -cz};

        float bv = -1.0f; int bi = 0;
#pragma unroll
        for (int pr = 0; pr < 8; ++pr) {
            v2f dx = pk_add(px[pr], ncx);
            v2f dy = pk_add(py[pr], ncy);
            v2f dz = pk_add(pz[pr], ncz);
            v2f s  = pk_add(pk_mul(dx, dx), pk_mul(dy, dy));
            v2f d2 = pk_add(s, pk_mul(dz, dz));
            float m0 = fminf(mind[pr].x, d2.x);
            float m1 = fminf(mind[pr].y, d2.y);
            mind[pr].x = m0; mind[pr].y = m1;
            if (m0 > bv) { bv = m0; bi = (2 * pr + 0) * 256 + t; }
            if (m1 > bv) { bv = m1; bi = (2 * pr + 1) * 256 + t; }
        }

        u64 key = ((u64)__float_as_uint(bv) << 32) | (u32)(~bi);
        key = wave_max_u64_dpp(key);

        const int p = it & 1;
        if (lane == 63) part[p * 4 + wv] = key;
        __syncthreads();

        u64 k0 = part[p * 4 + 0];
        u64 k1 = part[p * 4 + 1];
        u64 k2 = part[p * 4 + 2];
        u64 k3 = part[p * 4 + 3];
        u64 ka = k0 > k1 ? k0 : k1;
        u64 kb = k2 > k3 ? k2 : k3;
        u64 km = ka > kb ? ka : kb;
        int pick = (int)(~(u32)km);

        float4 cc = lp[pick];
        cx = cc.x; cy = cc.y; cz = cc.z;

        if (t < 8) {
            if ((it & 7) == t) mypick = pick;       // register capture
            if ((it & 7) == 7)                       // flush slots [it-7, it]
                __hip_atomic_store(&sel[b * MPER + (it - 7) + t],
                                   b * NPTS + mypick,
                                   __ATOMIC_RELAXED, __HIP_MEMORY_SCOPE_AGENT);
        }
    }
}

// ---- worker: queue -> sentinel-poll sel[c] -> ballq -> MFMA MLP -> outputs ----
__device__ __forceinline__ void worker_loop(
    char* smem, const float* __restrict__ pos, const float* __restrict__ x,
    const unsigned short* __restrict__ wsW,
    const float* __restrict__ b1, const float* __restrict__ b2,
    const float* __restrict__ b3,
    int* __restrict__ sel, int* __restrict__ wq,
    float* __restrict__ out_x, float* __restrict__ out_pos,
    float* __restrict__ out_batch)
{
    const int t = threadIdx.x;
    const int l = t & 63, w = t >> 6, lr = l & 15, kg = l >> 4;

    unsigned short* sW   = (unsigned short*)smem;              // 40960 B
    unsigned short* sA1  = (unsigned short*)(smem + 40960);    // [64][104]
    unsigned short* sH1  = (unsigned short*)(smem + 54272);    // [64][72]
    unsigned short* sH2  = (unsigned short*)(smem + 63488);    // [64][72]
    float* cd   = (float*)(smem + 72704);                      // [4][128]
    int*   ci   = (int*)(smem + 74752);                        // [4][128]
    int*   nbrl = (int*)(smem + 76800);                        // [64]
    int*   scnt = (int*)(smem + 77056);                        // [4]
    float* sq   = (float*)(smem + 77072);                      // [3]
    int*   sslot= (int*)(smem + 77084);                        // [1]

    // stage weights once (persist across centroids)
    {
        const uint4* src = (const uint4*)wsW;
        uint4* dst = (uint4*)sW;
#pragma unroll
        for (int i = 0; i < 10; ++i) dst[t + 256 * i] = src[t + 256 * i];
    }
    float bias1[4], bias2[4];
#pragma unroll
    for (int nt = 0; nt < 4; ++nt) {
        bias1[nt] = b1[nt * 16 + lr];
        bias2[nt] = b2[nt * 16 + lr];
    }
    const float b3r = (t < 128) ? b3[t] : 0.0f;

    const unsigned short* W1t = sW;                 // stride 104
    const unsigned short* W2t = sW + W1T_U;         // stride 72
    const unsigned short* W3t = sW + W1T_U + W2T_U; // stride 72

    for (;;) {
        if (t == 0) {
            int s = __hip_atomic_fetch_add(wq, 1, __ATOMIC_RELAXED,
                                           __HIP_MEMORY_SCOPE_AGENT);
            sslot[0] = s;
            if (s < MTOT) {
                const int it = s >> 3, b = s & 7;
                const int c = b * MPER + it;
                int sg;
                do {
                    sg = __hip_atomic_load(&sel[c], __ATOMIC_RELAXED,
                                           __HIP_MEMORY_SCOPE_AGENT);
                    if (sg < 0) __builtin_amdgcn_s_sleep(64);
                } while (sg < 0);
                float qx = pos[(size_t)sg * 3 + 0];
                float qy = pos[(size_t)sg * 3 + 1];
                float qz = pos[(size_t)sg * 3 + 2];
                sq[0] = qx; sq[1] = qy; sq[2] = qz;
                out_pos[(size_t)c * 3 + 0] = qx;
                out_pos[(size_t)c * 3 + 1] = qy;
                out_pos[(size_t)c * 3 + 2] = qz;
                out_batch[c] = (float)b;
            }
        }
        __syncthreads();
        const int s = sslot[0];
        if (s >= MTOT) break;                        // block-uniform exit
        const int it = s >> 3, b = s & 7;
        const int c = b * MPER + it;
        const float qx = sq[0], qy = sq[1], qz = sq[2];

        // ---- ballq: wave w scans quarter [w*1024,(w+1)*1024); rank select is
        // order-independent, so the 4-way segmented compaction preserves output
        const float* pb2 = pos + (size_t)b * NPTS * 3;
        int nw = 0;
        for (int r0 = 0; r0 < 1024; r0 += 64) {
            int j = w * 1024 + r0 + l;
            float xx = pb2[j * 3 + 0], yy = pb2[j * 3 + 1], zz = pb2[j * 3 + 2];
            float d2 = d2f(xx, yy, zz, qx, qy, qz);
            bool inside = ((double)d2 <= R2D);
            u64 m = __ballot(inside);
            if (inside) {
                int off = nw + __popcll(m & ((1ull << l) - 1ull));
                if (off < 128) { cd[w * 128 + off] = d2; ci[w * 128 + off] = j; }
            }
            nw += __popcll(m);
        }
        nw = min(nw, 128);
        if (l == 0) scnt[w] = nw;
        __syncthreads();
        const int n0 = scnt[0], n1 = scnt[1], n2 = scnt[2], n3 = scnt[3];
        const int ntot = n0 + n1 + n2 + n3;
        const int cnt = min(ntot, KNN);

        for (int f = t; f < ntot; f += 256) {
            int w2, i2;
            if (f < n0)                { w2 = 0; i2 = f; }
            else if (f < n0 + n1)      { w2 = 1; i2 = f - n0; }
            else if (f < n0 + n1 + n2) { w2 = 2; i2 = f - n0 - n1; }
            else                       { w2 = 3; i2 = f - n0 - n1 - n2; }
            float d = cd[w2 * 128 + i2]; int id = ci[w2 * 128 + i2];
            int rank = 0;
#pragma unroll
            for (int w3 = 0; w3 < 4; ++w3) {
                int nn = scnt[w3];
                for (int j = 0; j < nn; ++j) {
                    float dj = cd[w3 * 128 + j]; int ij = ci[w3 * 128 + j];
                    rank += (dj < d || (dj == d && ij < id)) ? 1 : 0;
                }
            }
            if (rank < KNN) nbrl[rank] = id;
        }
        __syncthreads();

        // ---- A1 staging: row k = [bf16(x[nb]), bf16(pos[nb]-q), zeros] ----
        {
            const int k = t >> 2, g = t & 3;
            const bool valid = k < cnt;
            const int nbg = valid ? (b * NPTS + nbrl[k]) : 0;
            const float* xr = x + (size_t)nbg * CIN + g * 16;
            float4 f0, f1, f2, f3;
            if (valid) {
                f0 = *(const float4*)(xr + 0);
                f1 = *(const float4*)(xr + 4);
                f2 = *(const float4*)(xr + 8);
                f3 = *(const float4*)(xr + 12);
            } else {
                f0 = float4{0.f, 0.f, 0.f, 0.f};
                f1 = f0; f2 = f0; f3 = f0;
            }
            uint4 ua = { pk2(f0.x, f0.y), pk2(f0.z, f0.w), pk2(f1.x, f1.y), pk2(f1.z, f1.w) };
            uint4 ub = { pk2(f2.x, f2.y), pk2(f2.z, f2.w), pk2(f3.x, f3.y), pk2(f3.z, f3.w) };
            *(uint4*)&sA1[k * 104 + g * 16 + 0] = ua;
            *(uint4*)&sA1[k * 104 + g * 16 + 8] = ub;
            if (g == 0) {
                float r0 = 0.f, r1 = 0.f, r2 = 0.f;
                if (valid) {
                    r0 = __fsub_rn(pos[(size_t)nbg * 3 + 0], qx);
                    r1 = __fsub_rn(pos[(size_t)nbg * 3 + 1], qy);
                    r2 = __fsub_rn(pos[(size_t)nbg * 3 + 2], qz);
                }
                uint4 uz = { 0u, 0u, 0u, 0u };
                uint4 ur = { pk2(r0, r1), (u32)f2bf(r2), 0u, 0u };
                *(uint4*)&sA1[k * 104 + 64] = ur;
                *(uint4*)&sA1[k * 104 + 72] = uz;
                *(uint4*)&sA1[k * 104 + 80] = uz;
                *(uint4*)&sA1[k * 104 + 88] = uz;
                *(uint4*)&sA1[k * 104 + 96] = uz;
            }
        }
        __syncthreads();

        // ---- layer 1: A1 x W1t -> H1 (relu) ----
        f32x4 acc1[4];
#pragma unroll
        for (int nt = 0; nt < 4; ++nt) acc1[nt] = f32x4{0.f, 0.f, 0.f, 0.f};
        {
            const int ao = (w * 16 + lr) * 104 + kg * 8;
            const int bo = lr * 104 + kg * 8;
#pragma unroll
            for (int kc = 0; kc < 3; ++kc) {
                s16x8 af = *(const s16x8*)&sA1[ao + kc * 32];
#pragma unroll
                for (int nt = 0; nt < 4; ++nt) {
                    s16x8 bf = *(const s16x8*)&W1t[bo + nt * 1664 + kc * 32];
                    acc1[nt] = mfma16(af, bf, acc1[nt]);
                }
            }
        }
#pragma unroll
        for (int nt = 0; nt < 4; ++nt) {
            const int col = nt * 16 + lr;
#pragma unroll
            for (int r = 0; r < 4; ++r) {
                const int row = w * 16 + kg * 4 + r;
                float v = fmaxf(acc1[nt][r] + bias1[nt], 0.0f);
                sH1[row * 72 + col] = f2bf(v);
            }
        }
        __syncthreads();

        // ---- layer 2: H1 x W2t -> H2 (relu) ----
        f32x4 acc2[4];
#pragma unroll
        for (int nt = 0; nt < 4; ++nt) acc2[nt] = f32x4{0.f, 0.f, 0.f, 0.f};
        {
            const int ao = (w * 16 + lr) * 72 + kg * 8;
            const int bo = lr * 72 + kg * 8;
#pragma unroll
            for (int kc = 0; kc < 2; ++kc) {
                s16x8 af = *(const s16x8*)&sH1[ao + kc * 32];
#pragma unroll
                for (int nt = 0; nt < 4; ++nt) {
                    s16x8 bf = *(const s16x8*)&W2t[bo + nt * 1152 + kc * 32];
                    acc2[nt] = mfma16(af, bf, acc2[nt]);
                }
            }
        }
#pragma unroll
        for (int nt = 0; nt < 4; ++nt) {
            const int col = nt * 16 + lr;
#pragma unroll
            for (int r = 0; r < 4; ++r) {
                const int row = w * 16 + kg * 4 + r;
                float v = fmaxf(acc2[nt][r] + bias2[nt], 0.0f);
                sH2[row * 72 + col] = f2bf(v);
            }
        }
        __syncthreads();

        // ---- layer 3: H2 x W3t ----
        f32x4 acc3[8];
#pragma unroll
        for (int nt = 0; nt < 8; ++nt) acc3[nt] = f32x4{0.f, 0.f, 0.f, 0.f};
        {
            const int ao = (w * 16 + lr) * 72 + kg * 8;
            const int bo = lr * 72 + kg * 8;
#pragma unroll
            for (int kc = 0; kc < 2; ++kc) {
                s16x8 af = *(const s16x8*)&sH2[ao + kc * 32];
#pragma unroll
                for (int nt = 0; nt < 8; ++nt) {
                    s16x8 bf = *(const s16x8*)&W3t[bo + nt * 1152 + kc * 32];
                    acc3[nt] = mfma16(af, bf, acc3[nt]);
                }
            }
        }

        // ---- masked max (bias after max: column-constant) ----
        float pm[8];
#pragma unroll
        for (int nt = 0; nt < 8; ++nt) pm[nt] = -1e30f;
#pragma unroll
        for (int r = 0; r < 4; ++r) {
            const int row = w * 16 + kg * 4 + r;
            if (row < cnt) {
#pragma unroll
                for (int nt = 0; nt < 8; ++nt) pm[nt] = fmaxf(pm[nt], acc3[nt][r]);
            }
        }
#pragma unroll
        for (int nt = 0; nt < 8; ++nt) {
            pm[nt] = fmaxf(pm[nt], __shfl_xor(pm[nt], 16));
            pm[nt] = fmaxf(pm[nt], __shfl_xor(pm[nt], 32));
        }
        __syncthreads();            // cd/ci dead; reuse as f32 partial [4][128]
        float* pbuf = cd;
        if (kg == 0) {
#pragma unroll
            for (int nt = 0; nt < 8; ++nt) pbuf[w * 128 + nt * 16 + lr] = pm[nt];
        }
        __syncthreads();
        if (t < 128) {
            float m = fmaxf(fmaxf(pbuf[t], pbuf[128 + t]),
                            fmaxf(pbuf[256 + t], pbuf[384 + t]));
            out_x[(size_t)c * 128 + t] = m + b3r;
        }
        // loop-top barrier (after slot grab) orders pbuf reads vs next cd write
    }
}

__global__ __launch_bounds__(256) void fused_kernel(
    const float* __restrict__ pos, const float* __restrict__ x,
    const unsigned short* __restrict__ wsW,
    const float* __restrict__ b1, const float* __restrict__ b2,
    const float* __restrict__ b3,
    int* __restrict__ sel, int* __restrict__ wq,
    float* __restrict__ out_x, float* __restrict__ out_pos,
    float* __restrict__ out_batch)
{
    extern __shared__ char smem[];
    if (blockIdx.x < NB) {
        fps_body(smem, pos, sel);
        __syncthreads();            // then join the worker pool (CU was idle)
    }
    worker_loop(smem, pos, x, wsW, b1, b2, b3, sel, wq,
                out_x, out_pos, out_batch);
}

extern "C" void kernel_launch(void* const* d_in, const int* in_sizes, int n_in,
                              void* d_out, int out_size, void* d_ws, size_t ws_size,
                              hipStream_t stream)
{
    const float* x   = (const float*)d_in[0];
    const float* pos = (const float*)d_in[1];
    const float* W1 = (const float*)d_in[3];
    const float* b1 = (const float*)d_in[4];
    const float* W2 = (const float*)d_in[5];
    const float* b2 = (const float*)d_in[6];
    const float* W3 = (const float*)d_in[7];
    const float* b3 = (const float*)d_in[8];

    float* out_x     = (float*)d_out;                    // [8192,128]
    float* out_pos   = out_x + (size_t)MTOT * 128;       // [8192,3]
    float* out_batch = out_pos + (size_t)MTOT * 3;       // [8192]

    int* sel = (int*)d_ws;                               // [8192], -1 = unpublished
    int* wq  = sel + MTOT;                               // [16] (1 used)
    unsigned short* wsW = (unsigned short*)(wq + 16);    // [20480] bf16 weights

    (void)hipFuncSetAttribute((const void*)fused_kernel,
                              hipFuncAttributeMaxDynamicSharedMemorySize, 86016);

    prep_weights<<<113, 256, 0, stream>>>(W1, W2, W3, wsW, sel, wq);
    fused_kernel<<<128, 256, 86016, stream>>>(pos, x, wsW, b1, b2, b3,
                                              sel, wq,
                                              out_x, out_pos, out_batch);
}

// Round 15
// 718.338 us; speedup vs baseline: 1.7388x; 1.7388x over previous
//
#include <hip/hip_runtime.h>
#include <math.h>

#define NB   8
#define NPTS 4096
#define MPER 1024
#define MTOT (NB*MPER)
#define CIN  64
#define KNN  64
#define CAP  512
// (0.2*0.2) computed in double, as the reference's python-float R*R
#define R2D  0.04000000000000001

typedef unsigned int u32;
typedef unsigned long long u64;
typedef float v2f __attribute__((ext_vector_type(2)));
using s16x8 = __attribute__((ext_vector_type(8))) short;   // 8 bf16 (4 VGPRs)
using f32x4 = __attribute__((ext_vector_type(4))) float;

// exact IEEE fp32 distance, reference order: ((dx*dx + dy*dy) + dz*dz), no FMA
__device__ __forceinline__ float d2f(float ax, float ay, float az,
                                     float bx, float by, float bz) {
    float dx = __fsub_rn(ax, bx);
    float dy = __fsub_rn(ay, by);
    float dz = __fsub_rn(az, bz);
    return __fadd_rn(__fadd_rn(__fmul_rn(dx, dx), __fmul_rn(dy, dy)),
                     __fmul_rn(dz, dz));
}

// CDNA packed 2xFP32 ops — IEEE-identical per component; asm, never contracted.
__device__ __forceinline__ v2f pk_add(v2f a, v2f b) {
    v2f d;
    asm("v_pk_add_f32 %0, %1, %2" : "=v"(d) : "v"(a), "v"(b));
    return d;
}
__device__ __forceinline__ v2f pk_mul(v2f a, v2f b) {
    v2f d;
    asm("v_pk_mul_f32 %0, %1, %2" : "=v"(d) : "v"(a), "v"(b));
    return d;
}

// float -> bf16 bits, round-to-nearest-even (finite inputs only)
__device__ __forceinline__ unsigned short f2bf(float f) {
    u32 x = __float_as_uint(f);
    u32 r = (x + 0x7fffu + ((x >> 16) & 1u)) >> 16;
    return (unsigned short)r;
}
__device__ __forceinline__ u32 pk2(float a, float b) {
    return (u32)f2bf(a) | ((u32)f2bf(b) << 16);
}

__device__ __forceinline__ f32x4 mfma16(s16x8 a, s16x8 b, f32x4 c) {
    return __builtin_amdgcn_mfma_f32_16x16x32_bf16(a, b, c, 0, 0, 0);
}

// full-wave (64-lane) max reduction of a u64 key via DPP; result valid in lane 63.
__device__ __forceinline__ u64 wave_max_u64_dpp(u64 key)
{
#define DPPMAX(ctrl, rmask) do {                                                   \
        u32 lo_ = (u32)key;                                                        \
        u32 hi_ = (u32)(key >> 32);                                                \
        u32 plo = (u32)__builtin_amdgcn_update_dpp(                                \
            0, (int)lo_, ctrl, rmask, 0xf, false);                                 \
        u32 phi = (u32)__builtin_amdgcn_update_dpp(                                \
            0, (int)hi_, ctrl, rmask, 0xf, false);                                 \
        u64 pk = ((u64)phi << 32) | plo;                                           \
        if (pk > key) key = pk;                                                    \
    } while (0)
    DPPMAX(0x111, 0xf);   // row_shr:1
    DPPMAX(0x112, 0xf);   // row_shr:2
    DPPMAX(0x114, 0xf);   // row_shr:4
    DPPMAX(0x118, 0xf);   // row_shr:8
    DPPMAX(0x142, 0xa);   // row_bcast:15 -> rows 1,3
    DPPMAX(0x143, 0xc);   // row_bcast:31 -> rows 2,3
#undef DPPMAX
    return key;
}

// ---------------- prep: bf16 weights (blk 0-79) + sel=-1 (blk 80-111) + wq ----
#define W1T_U 6656
#define W2T_U 4608
#define W3T_U 9216
#define WTOT_U 20480

__global__ __launch_bounds__(256) void prep_weights(
    const float* __restrict__ W1, const float* __restrict__ W2,
    const float* __restrict__ W3, unsigned short* __restrict__ wsW,
    int* __restrict__ sel, int* __restrict__ wq)
{
    const int bid = blockIdx.x;
    const int t = threadIdx.x;
    if (bid >= 112) {                     // wq init
        if (t == 0) *wq = 0;
        return;
    }
    if (bid >= 80) {                      // sel sentinel init (-1: unpublished)
        sel[(bid - 80) * 256 + t] = -1;
        return;
    }
    int i = bid * 256 + t;
    float v;
    if (i < W1T_U) {
        int cr = i / 104, k = i - cr * 104;
        v = (k < 67) ? W1[k * 64 + cr] : 0.0f;
    } else if (i < W1T_U + W2T_U) {
        int j = i - W1T_U;
        int cr = j / 72, k = j - cr * 72;
        v = (k < 64) ? W2[k * 64 + cr] : 0.0f;
    } else {
        int j = i - (W1T_U + W2T_U);
        int cr = j / 72, k = j - cr * 72;
        v = (k < 64) ? W3[k * 128 + cr] : 0.0f;
    }
    wsW[i] = f2bf(v);
}

// ================= fused kernel: 8 FPS blocks + 248 worker blocks ==============
// LDS = 90112 B -> 1 block/CU, all 256 blocks co-resident.
// r15: workers are WAVE-INDEPENDENT — each of the 4 waves owns its own slot
// (r14 lesson: block-serial worker = 18us/slot, no TLP; 4 independent waves/CU
// overlap each other's latency like 4 co-resident blocks). No __syncthreads in
// the worker loop; all scratch is per-wave; wave-internal LDS ordering is
// in-order DS + compiler lgkmcnt.

// ---- FPS producer (r12-proven: 8-batch register publish) ----
__device__ __forceinline__ void fps_body(char* smem, const float* __restrict__ pos,
                                         int* __restrict__ sel)
{
    const int b    = blockIdx.x;
    const int t    = threadIdx.x;
    const int lane = t & 63;
    const int wv   = t >> 6;
    const float* pb = pos + (size_t)b * NPTS * 3;

    float4* lp = (float4*)smem;              // 64 KB
    u64*    part = (u64*)(smem + 65536);     // [2][4]

    v2f px[8], py[8], pz[8], mind[8];
#pragma unroll
    for (int pr = 0; pr < 8; ++pr) {
        int j0 = (2 * pr + 0) * 256 + t;
        int j1 = (2 * pr + 1) * 256 + t;
        float x0 = pb[j0 * 3 + 0], y0 = pb[j0 * 3 + 1], z0 = pb[j0 * 3 + 2];
        float x1 = pb[j1 * 3 + 0], y1 = pb[j1 * 3 + 1], z1 = pb[j1 * 3 + 2];
        px[pr] = v2f{x0, x1}; py[pr] = v2f{y0, y1}; pz[pr] = v2f{z0, z1};
        mind[pr] = v2f{3.0e38f, 3.0e38f};
        lp[j0] = float4{x0, y0, z0, 0.f};
        lp[j1] = float4{x1, y1, z1, 0.f};
    }
    __syncthreads();

    float4 c0 = lp[0];
    float cx = c0.x, cy = c0.y, cz = c0.z;
    int mypick = 0;                          // t==0 carries slot-0 pick (idx 0)

    for (int it = 1; it < MPER; ++it) {
        const v2f ncx = v2f{-cx, -cx};
        const v2f ncy = v2f{-cy, -cy};
        const v2f ncz = v2f{-cz, -cz};

        float bv = -1.0f; int bi = 0;
#pragma unroll
        for (int pr = 0; pr < 8; ++pr) {
            v2f dx = pk_add(px[pr], ncx);
            v2f dy = pk_add(py[pr], ncy);
            v2f dz = pk_add(pz[pr], ncz);
            v2f s  = pk_add(pk_mul(dx, dx), pk_mul(dy, dy));
            v2f d2 = pk_add(s, pk_mul(dz, dz));
            float m0 = fminf(mind[pr].x, d2.x);
            float m1 = fminf(mind[pr].y, d2.y);
            mind[pr].x = m0; mind[pr].y = m1;
            if (m0 > bv) { bv = m0; bi = (2 * pr + 0) * 256 + t; }
            if (m1 > bv) { bv = m1; bi = (2 * pr + 1) * 256 + t; }
        }

        u64 key = ((u64)__float_as_uint(bv) << 32) | (u32)(~bi);
        key = wave_max_u64_dpp(key);

        const int p = it & 1;
        if (lane == 63) part[p * 4 + wv] = key;
        __syncthreads();

        u64 k0 = part[p * 4 + 0];
        u64 k1 = part[p * 4 + 1];
        u64 k2 = part[p * 4 + 2];
        u64 k3 = part[p * 4 + 3];
        u64 ka = k0 > k1 ? k0 : k1;
        u64 kb = k2 > k3 ? k2 : k3;
        u64 km = ka > kb ? ka : kb;
        int pick = (int)(~(u32)km);

        float4 cc = lp[pick];
        cx = cc.x; cy = cc.y; cz = cc.z;

        if (t < 8) {
            if ((it & 7) == t) mypick = pick;       // register capture
            if ((it & 7) == 7)                       // flush slots [it-7, it]
                __hip_atomic_store(&sel[b * MPER + (it - 7) + t],
                                   b * NPTS + mypick,
                                   __ATOMIC_RELAXED, __HIP_MEMORY_SCOPE_AGENT);
        }
    }
}

// ---- per-wave worker: slot grab -> poll -> 1-wave ballq -> 1-wave MFMA MLP ----
// per-wave LDS region (12288 B): cd[512] | ci[512] | A1[16][104] | H1[16][72]
//                                | H2[16][72] | nbrl[64]
__device__ __forceinline__ void worker_wave(
    char* smem, const float* __restrict__ pos, const float* __restrict__ x,
    const float* __restrict__ b1, const float* __restrict__ b2,
    const float* __restrict__ b3,
    int* __restrict__ sel, int* __restrict__ wq,
    float* __restrict__ out_x, float* __restrict__ out_pos,
    float* __restrict__ out_batch)
{
    const int l  = threadIdx.x & 63;
    const int w  = threadIdx.x >> 6;
    const int lr = l & 15;
    const int kg = l >> 4;

    char* wb = smem + 40960 + w * 12288;
    float* cd            = (float*)wb;                         // 2048 B
    int*   ci            = (int*)(wb + 2048);                  // 2048 B
    unsigned short* sA1  = (unsigned short*)(wb + 4096);       // 3328 B
    unsigned short* sH1  = (unsigned short*)(wb + 7424);       // 2304 B
    unsigned short* sH2  = (unsigned short*)(wb + 9728);       // 2304 B
    int*   nbrl          = (int*)(wb + 12032);                 // 256 B

    const unsigned short* W1t = (const unsigned short*)smem;   // stride 104
    const unsigned short* W2t = W1t + W1T_U;                   // stride 72
    const unsigned short* W3t = W1t + W1T_U + W2T_U;           // stride 72

    float bias1[4], bias2[4], bias3[8];
#pragma unroll
    for (int nt = 0; nt < 4; ++nt) {
        bias1[nt] = b1[nt * 16 + lr];
        bias2[nt] = b2[nt * 16 + lr];
    }
#pragma unroll
    for (int nt = 0; nt < 8; ++nt) bias3[nt] = b3[nt * 16 + lr];

    for (;;) {
        int s = 0;
        if (l == 0)
            s = __hip_atomic_fetch_add(wq, 1, __ATOMIC_RELAXED,
                                       __HIP_MEMORY_SCOPE_AGENT);
        s = __builtin_amdgcn_readfirstlane(s);
        if (s >= MTOT) return;
        const int it = s >> 3, b = s & 7;
        const int c = b * MPER + it;

        int sg = 0;
        if (l == 0) {
            do {
                sg = __hip_atomic_load(&sel[c], __ATOMIC_RELAXED,
                                       __HIP_MEMORY_SCOPE_AGENT);
                if (sg < 0) __builtin_amdgcn_s_sleep(32);
            } while (sg < 0);
        }
        sg = __builtin_amdgcn_readfirstlane(sg);

        const float qx = pos[(size_t)sg * 3 + 0];
        const float qy = pos[(size_t)sg * 3 + 1];
        const float qz = pos[(size_t)sg * 3 + 2];
        if (l == 0) {
            out_pos[(size_t)c * 3 + 0] = qx;
            out_pos[(size_t)c * 3 + 1] = qy;
            out_pos[(size_t)c * 3 + 2] = qz;
            out_batch[c] = (float)b;
        }

        // ---- single-wave ballq (r7-proven structure) ----
        const float* pb2 = pos + (size_t)b * NPTS * 3;
        int n = 0;
        for (int r0 = 0; r0 < NPTS; r0 += 64) {
            const int j = r0 + l;
            float xx = pb2[j * 3 + 0], yy = pb2[j * 3 + 1], zz = pb2[j * 3 + 2];
            float d2 = d2f(xx, yy, zz, qx, qy, qz);
            bool inside = ((double)d2 <= R2D);
            u64 m = __ballot(inside);
            if (inside) {
                int off = n + __popcll(m & ((1ull << l) - 1ull));
                if (off < CAP) { cd[off] = d2; ci[off] = j; }
            }
            n += __popcll(m);
        }
        n = min(n, CAP);

        // rank = #{j : (dj,ij) <lex (d,id)} — lax.top_k stable order
        for (int i = l; i < n; i += 64) {
            float d = cd[i]; int id = ci[i];
            int rank = 0;
            for (int j = 0; j < n; ++j) {
                float dj = cd[j]; int ij = ci[j];
                rank += (dj < d || (dj == d && ij < id)) ? 1 : 0;
            }
            if (rank < KNN) nbrl[rank] = id;
        }
        const int cnt = min(n, KNN);

        // ---- MLP over 4 row-groups of 16 neighbors; running masked max ----
        float pm[8];
#pragma unroll
        for (int nt = 0; nt < 8; ++nt) pm[nt] = -1e30f;

        for (int g = 0; g < 4; ++g) {
            // A1 staging: row kk = l>>2 (0..15), lane group gc = l&3
            {
                const int kk = l >> 2, gc = l & 3;
                const int grow = g * 16 + kk;
                const bool valid = grow < cnt;
                const int nbg = valid ? (b * NPTS + nbrl[grow]) : 0;
                const float* xr = x + (size_t)nbg * CIN + gc * 16;
                float4 f0, f1, f2, f3;
                if (valid) {
                    f0 = *(const float4*)(xr + 0);
                    f1 = *(const float4*)(xr + 4);
                    f2 = *(const float4*)(xr + 8);
                    f3 = *(const float4*)(xr + 12);
                } else {
                    f0 = float4{0.f, 0.f, 0.f, 0.f};
                    f1 = f0; f2 = f0; f3 = f0;
                }
                uint4 ua = { pk2(f0.x, f0.y), pk2(f0.z, f0.w),
                             pk2(f1.x, f1.y), pk2(f1.z, f1.w) };
                uint4 ub = { pk2(f2.x, f2.y), pk2(f2.z, f2.w),
                             pk2(f3.x, f3.y), pk2(f3.z, f3.w) };
                *(uint4*)&sA1[kk * 104 + gc * 16 + 0] = ua;
                *(uint4*)&sA1[kk * 104 + gc * 16 + 8] = ub;
                if (gc == 0) {
                    float r0 = 0.f, r1 = 0.f, r2 = 0.f;
                    if (valid) {
                        r0 = __fsub_rn(pos[(size_t)nbg * 3 + 0], qx);
                        r1 = __fsub_rn(pos[(size_t)nbg * 3 + 1], qy);
                        r2 = __fsub_rn(pos[(size_t)nbg * 3 + 2], qz);
                    }
                    uint4 uz = { 0u, 0u, 0u, 0u };
                    uint4 ur = { pk2(r0, r1), (u32)f2bf(r2), 0u, 0u };
                    *(uint4*)&sA1[kk * 104 + 64] = ur;
                    *(uint4*)&sA1[kk * 104 + 72] = uz;
                    *(uint4*)&sA1[kk * 104 + 80] = uz;
                    *(uint4*)&sA1[kk * 104 + 88] = uz;
                    *(uint4*)&sA1[kk * 104 + 96] = uz;
                }
            }

            // layer 1: A1[16][96+] x W1t -> H1 (relu)
            f32x4 acc1[4];
#pragma unroll
            for (int nt = 0; nt < 4; ++nt) acc1[nt] = f32x4{0.f, 0.f, 0.f, 0.f};
#pragma unroll
            for (int kc = 0; kc < 3; ++kc) {
                s16x8 af = *(const s16x8*)&sA1[lr * 104 + kg * 8 + kc * 32];
#pragma unroll
                for (int nt = 0; nt < 4; ++nt) {
                    s16x8 bf = *(const s16x8*)&W1t[lr * 104 + kg * 8 +
                                                   nt * 1664 + kc * 32];
                    acc1[nt] = mfma16(af, bf, acc1[nt]);
                }
            }
#pragma unroll
            for (int nt = 0; nt < 4; ++nt) {
                const int col = nt * 16 + lr;
#pragma unroll
                for (int r = 0; r < 4; ++r) {
                    const int row = kg * 4 + r;
                    float v = fmaxf(acc1[nt][r] + bias1[nt], 0.0f);
                    sH1[row * 72 + col] = f2bf(v);
                }
            }

            // layer 2: H1 x W2t -> H2 (relu)
            f32x4 acc2[4];
#pragma unroll
            for (int nt = 0; nt < 4; ++nt) acc2[nt] = f32x4{0.f, 0.f, 0.f, 0.f};
#pragma unroll
            for (int kc = 0; kc < 2; ++kc) {
                s16x8 af = *(const s16x8*)&sH1[lr * 72 + kg * 8 + kc * 32];
#pragma unroll
                for (int nt = 0; nt < 4; ++nt) {
                    s16x8 bf = *(const s16x8*)&W2t[lr * 72 + kg * 8 +
                                                   nt * 1152 + kc * 32];
                    acc2[nt] = mfma16(af, bf, acc2[nt]);
                }
            }
#pragma unroll
            for (int nt = 0; nt < 4; ++nt) {
                const int col = nt * 16 + lr;
#pragma unroll
                for (int r = 0; r < 4; ++r) {
                    const int row = kg * 4 + r;
                    float v = fmaxf(acc2[nt][r] + bias2[nt], 0.0f);
                    sH2[row * 72 + col] = f2bf(v);
                }
            }

            // layer 3: H2 x W3t; masked max into pm
            f32x4 acc3[8];
#pragma unroll
            for (int nt = 0; nt < 8; ++nt) acc3[nt] = f32x4{0.f, 0.f, 0.f, 0.f};
#pragma unroll
            for (int kc = 0; kc < 2; ++kc) {
                s16x8 af = *(const s16x8*)&sH2[lr * 72 + kg * 8 + kc * 32];
#pragma unroll
                for (int nt = 0; nt < 8; ++nt) {
                    s16x8 bf = *(const s16x8*)&W3t[lr * 72 + kg * 8 +
                                                   nt * 1152 + kc * 32];
                    acc3[nt] = mfma16(af, bf, acc3[nt]);
                }
            }
#pragma unroll
            for (int r = 0; r < 4; ++r) {
                const int grow = g * 16 + kg * 4 + r;
                if (grow < cnt) {
#pragma unroll
                    for (int nt = 0; nt < 8; ++nt)
                        pm[nt] = fmaxf(pm[nt], acc3[nt][r]);
                }
            }
        }

        // cross-lane max over kg groups; col = nt*16 + lr
#pragma unroll
        for (int nt = 0; nt < 8; ++nt) {
            pm[nt] = fmaxf(pm[nt], __shfl_xor(pm[nt], 16));
            pm[nt] = fmaxf(pm[nt], __shfl_xor(pm[nt], 32));
        }
        if (l < 16) {
#pragma unroll
            for (int nt = 0; nt < 8; ++nt)
                out_x[(size_t)c * 128 + nt * 16 + lr] = pm[nt] + bias3[nt];
        }
    }
}

__global__ __launch_bounds__(256) void fused_kernel(
    const float* __restrict__ pos, const float* __restrict__ x,
    const unsigned short* __restrict__ wsW,
    const float* __restrict__ b1, const float* __restrict__ b2,
    const float* __restrict__ b3,
    int* __restrict__ sel, int* __restrict__ wq,
    float* __restrict__ out_x, float* __restrict__ out_pos,
    float* __restrict__ out_batch)
{
    extern __shared__ char smem[];
    const int t = threadIdx.x;

    if (blockIdx.x < NB)
        fps_body(smem, pos, sel);          // uses smem[0..65600) as lp/part

    // stage weights (workers: immediately; FPS blocks: after fps_body, lp dead)
    {
        const uint4* src = (const uint4*)wsW;
        uint4* dst = (uint4*)smem;
#pragma unroll
        for (int i = 0; i < 10; ++i) dst[t + 256 * i] = src[t + 256 * i];
    }
    __syncthreads();

    worker_wave(smem, pos, x, b1, b2, b3, sel, wq, out_x, out_pos, out_batch);
}

extern "C" void kernel_launch(void* const* d_in, const int* in_sizes, int n_in,
                              void* d_out, int out_size, void* d_ws, size_t ws_size,
                              hipStream_t stream)
{
    const float* x   = (const float*)d_in[0];
    const float* pos = (const float*)d_in[1];
    const float* W1 = (const float*)d_in[3];
    const float* b1 = (const float*)d_in[4];
    const float* W2 = (const float*)d_in[5];
    const float* b2 = (const float*)d_in[6];
    const float* W3 = (const float*)d_in[7];
    const float* b3 = (const float*)d_in[8];

    float* out_x     = (float*)d_out;                    // [8192,128]
    float* out_pos   = out_x + (size_t)MTOT * 128;       // [8192,3]
    float* out_batch = out_pos + (size_t)MTOT * 3;       // [8192]

    int* sel = (int*)d_ws;                               // [8192], -1 = unpublished
    int* wq  = sel + MTOT;                               // [16] (1 used)
    unsigned short* wsW = (unsigned short*)(wq + 16);    // [20480] bf16 weights

    (void)hipFuncSetAttribute((const void*)fused_kernel,
                              hipFuncAttributeMaxDynamicSharedMemorySize, 90112);

    prep_weights<<<113, 256, 0, stream>>>(W1, W2, W3, wsW, sel, wq);
    fused_kernel<<<256, 256, 90112, stream>>>(pos, x, wsW, b1, b2, b3,
                                              sel, wq,
                                              out_x, out_pos, out_batch);
}

// Round 16
// 680.364 us; speedup vs baseline: 1.8358x; 1.0558x over previous
//
#include <hip/hip_runtime.h>
#include <math.h>

#define NB   8
#define NPTS 4096
#define MPER 1024
#define MTOT (NB*MPER)
#define CIN  64
#define KNN  64
// (0.2*0.2) computed in double, as the reference's python-float R*R
#define R2D  0.04000000000000001

typedef unsigned int u32;
typedef unsigned long long u64;
typedef float v2f __attribute__((ext_vector_type(2)));
using s16x8 = __attribute__((ext_vector_type(8))) short;   // 8 bf16 (4 VGPRs)
using f32x4 = __attribute__((ext_vector_type(4))) float;

// exact IEEE fp32 distance, reference order: ((dx*dx + dy*dy) + dz*dz), no FMA
__device__ __forceinline__ float d2f(float ax, float ay, float az,
                                     float bx, float by, float bz) {
    float dx = __fsub_rn(ax, bx);
    float dy = __fsub_rn(ay, by);
    float dz = __fsub_rn(az, bz);
    return __fadd_rn(__fadd_rn(__fmul_rn(dx, dx), __fmul_rn(dy, dy)),
                     __fmul_rn(dz, dz));
}

// CDNA packed 2xFP32 ops — IEEE-identical per component; asm, never contracted.
__device__ __forceinline__ v2f pk_add(v2f a, v2f b) {
    v2f d;
    asm("v_pk_add_f32 %0, %1, %2" : "=v"(d) : "v"(a), "v"(b));
    return d;
}
__device__ __forceinline__ v2f pk_mul(v2f a, v2f b) {
    v2f d;
    asm("v_pk_mul_f32 %0, %1, %2" : "=v"(d) : "v"(a), "v"(b));
    return d;
}

// float -> bf16 bits, round-to-nearest-even (finite inputs only)
__device__ __forceinline__ unsigned short f2bf(float f) {
    u32 x = __float_as_uint(f);
    u32 r = (x + 0x7fffu + ((x >> 16) & 1u)) >> 16;
    return (unsigned short)r;
}
__device__ __forceinline__ u32 pk2(float a, float b) {
    return (u32)f2bf(a) | ((u32)f2bf(b) << 16);
}

__device__ __forceinline__ f32x4 mfma16(s16x8 a, s16x8 b, f32x4 c) {
    return __builtin_amdgcn_mfma_f32_16x16x32_bf16(a, b, c, 0, 0, 0);
}

// full-wave (64-lane) max reduction of a u64 key via DPP; result valid in lane 63.
__device__ __forceinline__ u64 wave_max_u64_dpp(u64 key)
{
#define DPPMAX(ctrl, rmask) do {                                                   \
        u32 lo_ = (u32)key;                                                        \
        u32 hi_ = (u32)(key >> 32);                                                \
        u32 plo = (u32)__builtin_amdgcn_update_dpp(                                \
            0, (int)lo_, ctrl, rmask, 0xf, false);                                 \
        u32 phi = (u32)__builtin_amdgcn_update_dpp(                                \
            0, (int)hi_, ctrl, rmask, 0xf, false);                                 \
        u64 pk = ((u64)phi << 32) | plo;                                           \
        if (pk > key) key = pk;                                                    \
    } while (0)
    DPPMAX(0x111, 0xf);   // row_shr:1
    DPPMAX(0x112, 0xf);   // row_shr:2
    DPPMAX(0x114, 0xf);   // row_shr:4
    DPPMAX(0x118, 0xf);   // row_shr:8
    DPPMAX(0x142, 0xa);   // row_bcast:15 -> rows 1,3
    DPPMAX(0x143, 0xc);   // row_bcast:31 -> rows 2,3
#undef DPPMAX
    return key;
}

// ---------------- prep: bf16 weights (blk 0-79) + sel=-1 (blk 80-111) + wq ----
#define W1T_U 6656
#define W2T_U 4608
#define W3T_U 9216
#define WTOT_U 20480

__global__ __launch_bounds__(256) void prep_weights(
    const float* __restrict__ W1, const float* __restrict__ W2,
    const float* __restrict__ W3, unsigned short* __restrict__ wsW,
    int* __restrict__ sel, int* __restrict__ wq)
{
    const int bid = blockIdx.x;
    const int t = threadIdx.x;
    if (bid >= 112) {                     // wq init
        if (t == 0) *wq = 0;
        return;
    }
    if (bid >= 80) {                      // sel sentinel init (-1: unpublished)
        sel[(bid - 80) * 256 + t] = -1;
        return;
    }
    int i = bid * 256 + t;
    float v;
    if (i < W1T_U) {
        int cr = i / 104, k = i - cr * 104;
        v = (k < 67) ? W1[k * 64 + cr] : 0.0f;
    } else if (i < W1T_U + W2T_U) {
        int j = i - W1T_U;
        int cr = j / 72, k = j - cr * 72;
        v = (k < 64) ? W2[k * 64 + cr] : 0.0f;
    } else {
        int j = i - (W1T_U + W2T_U);
        int cr = j / 72, k = j - cr * 72;
        v = (k < 64) ? W3[k * 128 + cr] : 0.0f;
    }
    wsW[i] = f2bf(v);
}

// ================= fused kernel: 8 FPS blocks + 248 persistent workers =========
// r12 champion (677.8us) verbatim; one marginal tweak: poll s_sleep 64 -> 127
// (halves coherent-point poll traffic; poll period ~4us << 18us slot work).
// Structural floor: total ~= serial FPS chain (1023 dependent iterations of
// phase-A + DPP reduce + barrier + LDS tail) at the all-CU throttled clock
// (591us standalone x 2.4/2.08 GHz ~= 682us) with ballq+MLP fully overlapped.

// ---- FPS producer (r7-proven compute structure; 8-batch register publish) ----
__device__ __forceinline__ void fps_body(char* smem, const float* __restrict__ pos,
                                         int* __restrict__ sel)
{
    const int b    = blockIdx.x;
    const int t    = threadIdx.x;
    const int lane = t & 63;
    const int wv   = t >> 6;
    const float* pb = pos + (size_t)b * NPTS * 3;

    float4* lp = (float4*)smem;              // 64 KB
    u64*    part = (u64*)(smem + 65536);     // [2][4]

    v2f px[8], py[8], pz[8], mind[8];
#pragma unroll
    for (int pr = 0; pr < 8; ++pr) {
        int j0 = (2 * pr + 0) * 256 + t;
        int j1 = (2 * pr + 1) * 256 + t;
        float x0 = pb[j0 * 3 + 0], y0 = pb[j0 * 3 + 1], z0 = pb[j0 * 3 + 2];
        float x1 = pb[j1 * 3 + 0], y1 = pb[j1 * 3 + 1], z1 = pb[j1 * 3 + 2];
        px[pr] = v2f{x0, x1}; py[pr] = v2f{y0, y1}; pz[pr] = v2f{z0, z1};
        mind[pr] = v2f{3.0e38f, 3.0e38f};
        lp[j0] = float4{x0, y0, z0, 0.f};
        lp[j1] = float4{x1, y1, z1, 0.f};
    }
    __syncthreads();

    float4 c0 = lp[0];
    float cx = c0.x, cy = c0.y, cz = c0.z;
    int mypick = 0;                          // t==0 carries slot-0 pick (idx 0)

    for (int it = 1; it < MPER; ++it) {
        const v2f ncx = v2f{-cx, -cx};
        const v2f ncy = v2f{-cy, -cy};
        const v2f ncz = v2f{-cz, -cz};

        float bv = -1.0f; int bi = 0;
#pragma unroll
        for (int pr = 0; pr < 8; ++pr) {
            v2f dx = pk_add(px[pr], ncx);
            v2f dy = pk_add(py[pr], ncy);
            v2f dz = pk_add(pz[pr], ncz);
            v2f s  = pk_add(pk_mul(dx, dx), pk_mul(dy, dy));
            v2f d2 = pk_add(s, pk_mul(dz, dz));
            float m0 = fminf(mind[pr].x, d2.x);
            float m1 = fminf(mind[pr].y, d2.y);
            mind[pr].x = m0; mind[pr].y = m1;
            if (m0 > bv) { bv = m0; bi = (2 * pr + 0) * 256 + t; }
            if (m1 > bv) { bv = m1; bi = (2 * pr + 1) * 256 + t; }
        }

        u64 key = ((u64)__float_as_uint(bv) << 32) | (u32)(~bi);
        key = wave_max_u64_dpp(key);

        const int p = it & 1;
        if (lane == 63) part[p * 4 + wv] = key;
        __syncthreads();

        u64 k0 = part[p * 4 + 0];
        u64 k1 = part[p * 4 + 1];
        u64 k2 = part[p * 4 + 2];
        u64 k3 = part[p * 4 + 3];
        u64 ka = k0 > k1 ? k0 : k1;
        u64 kb = k2 > k3 ? k2 : k3;
        u64 km = ka > kb ? ka : kb;
        int pick = (int)(~(u32)km);

        float4 cc = lp[pick];
        cx = cc.x; cy = cc.y; cz = cc.z;

        if (t < 8) {
            if ((it & 7) == t) mypick = pick;       // register capture
            if ((it & 7) == 7)                       // flush slots [it-7, it]
                __hip_atomic_store(&sel[b * MPER + (it - 7) + t],
                                   b * NPTS + mypick,
                                   __ATOMIC_RELAXED, __HIP_MEMORY_SCOPE_AGENT);
        }
    }
}

// ---- worker: queue -> sentinel-poll sel[c] -> ballq -> MFMA MLP -> outputs ----
__device__ __forceinline__ void worker_loop(
    char* smem, const float* __restrict__ pos, const float* __restrict__ x,
    const unsigned short* __restrict__ wsW,
    const float* __restrict__ b1, const float* __restrict__ b2,
    const float* __restrict__ b3,
    int* __restrict__ sel, int* __restrict__ wq,
    float* __restrict__ out_x, float* __restrict__ out_pos,
    float* __restrict__ out_batch)
{
    const int t = threadIdx.x;
    const int l = t & 63, w = t >> 6, lr = l & 15, kg = l >> 4;

    unsigned short* sW   = (unsigned short*)smem;              // 40960 B
    unsigned short* sA1  = (unsigned short*)(smem + 40960);    // [64][104]
    unsigned short* sH1  = (unsigned short*)(smem + 54272);    // [64][72]
    unsigned short* sH2  = (unsigned short*)(smem + 63488);    // [64][72]
    float* cd   = (float*)(smem + 72704);                      // [4][128]
    int*   ci   = (int*)(smem + 74752);                        // [4][128]
    int*   nbrl = (int*)(smem + 76800);                        // [64]
    int*   scnt = (int*)(smem + 77056);                        // [4]
    float* sq   = (float*)(smem + 77072);                      // [3]
    int*   sslot= (int*)(smem + 77084);                        // [1]

    // stage weights once (persist across centroids)
    {
        const uint4* src = (const uint4*)wsW;
        uint4* dst = (uint4*)sW;
#pragma unroll
        for (int i = 0; i < 10; ++i) dst[t + 256 * i] = src[t + 256 * i];
    }
    float bias1[4], bias2[4];
#pragma unroll
    for (int nt = 0; nt < 4; ++nt) {
        bias1[nt] = b1[nt * 16 + lr];
        bias2[nt] = b2[nt * 16 + lr];
    }
    const float b3r = (t < 128) ? b3[t] : 0.0f;

    const unsigned short* W1t = sW;                 // stride 104
    const unsigned short* W2t = sW + W1T_U;         // stride 72
    const unsigned short* W3t = sW + W1T_U + W2T_U; // stride 72

    for (;;) {
        if (t == 0) {
            int s = __hip_atomic_fetch_add(wq, 1, __ATOMIC_RELAXED,
                                           __HIP_MEMORY_SCOPE_AGENT);
            sslot[0] = s;
            if (s < MTOT) {
                const int it = s >> 3, b = s & 7;
                const int c = b * MPER + it;
                int sg;
                do {
                    sg = __hip_atomic_load(&sel[c], __ATOMIC_RELAXED,
                                           __HIP_MEMORY_SCOPE_AGENT);
                    if (sg < 0) __builtin_amdgcn_s_sleep(127);
                } while (sg < 0);
                float qx = pos[(size_t)sg * 3 + 0];
                float qy = pos[(size_t)sg * 3 + 1];
                float qz = pos[(size_t)sg * 3 + 2];
                sq[0] = qx; sq[1] = qy; sq[2] = qz;
                out_pos[(size_t)c * 3 + 0] = qx;
                out_pos[(size_t)c * 3 + 1] = qy;
                out_pos[(size_t)c * 3 + 2] = qz;
                out_batch[c] = (float)b;
            }
        }
        __syncthreads();
        const int s = sslot[0];
        if (s >= MTOT) break;                        // block-uniform exit
        const int it = s >> 3, b = s & 7;
        const int c = b * MPER + it;
        const float qx = sq[0], qy = sq[1], qz = sq[2];

        // ---- ballq: wave w scans quarter [w*1024,(w+1)*1024); rank select is
        // order-independent, so the 4-way segmented compaction preserves output
        const float* pb2 = pos + (size_t)b * NPTS * 3;
        int nw = 0;
        for (int r0 = 0; r0 < 1024; r0 += 64) {
            int j = w * 1024 + r0 + l;
            float xx = pb2[j * 3 + 0], yy = pb2[j * 3 + 1], zz = pb2[j * 3 + 2];
            float d2 = d2f(xx, yy, zz, qx, qy, qz);
            bool inside = ((double)d2 <= R2D);
            u64 m = __ballot(inside);
            if (inside) {
                int off = nw + __popcll(m & ((1ull << l) - 1ull));
                if (off < 128) { cd[w * 128 + off] = d2; ci[w * 128 + off] = j; }
            }
            nw += __popcll(m);
        }
        nw = min(nw, 128);
        if (l == 0) scnt[w] = nw;
        __syncthreads();
        const int n0 = scnt[0], n1 = scnt[1], n2 = scnt[2], n3 = scnt[3];
        const int ntot = n0 + n1 + n2 + n3;
        const int cnt = min(ntot, KNN);

        for (int f = t; f < ntot; f += 256) {
            int w2, i2;
            if (f < n0)                { w2 = 0; i2 = f; }
            else if (f < n0 + n1)      { w2 = 1; i2 = f - n0; }
            else if (f < n0 + n1 + n2) { w2 = 2; i2 = f - n0 - n1; }
            else                       { w2 = 3; i2 = f - n0 - n1 - n2; }
            float d = cd[w2 * 128 + i2]; int id = ci[w2 * 128 + i2];
            int rank = 0;
#pragma unroll
            for (int w3 = 0; w3 < 4; ++w3) {
                int nn = scnt[w3];
                for (int j = 0; j < nn; ++j) {
                    float dj = cd[w3 * 128 + j]; int ij = ci[w3 * 128 + j];
                    rank += (dj < d || (dj == d && ij < id)) ? 1 : 0;
                }
            }
            if (rank < KNN) nbrl[rank] = id;
        }
        __syncthreads();

        // ---- A1 staging: row k = [bf16(x[nb]), bf16(pos[nb]-q), zeros] ----
        {
            const int k = t >> 2, g = t & 3;
            const bool valid = k < cnt;
            const int nbg = valid ? (b * NPTS + nbrl[k]) : 0;
            const float* xr = x + (size_t)nbg * CIN + g * 16;
            float4 f0, f1, f2, f3;
            if (valid) {
                f0 = *(const float4*)(xr + 0);
                f1 = *(const float4*)(xr + 4);
                f2 = *(const float4*)(xr + 8);
                f3 = *(const float4*)(xr + 12);
            } else {
                f0 = float4{0.f, 0.f, 0.f, 0.f};
                f1 = f0; f2 = f0; f3 = f0;
            }
            uint4 ua = { pk2(f0.x, f0.y), pk2(f0.z, f0.w), pk2(f1.x, f1.y), pk2(f1.z, f1.w) };
            uint4 ub = { pk2(f2.x, f2.y), pk2(f2.z, f2.w), pk2(f3.x, f3.y), pk2(f3.z, f3.w) };
            *(uint4*)&sA1[k * 104 + g * 16 + 0] = ua;
            *(uint4*)&sA1[k * 104 + g * 16 + 8] = ub;
            if (g == 0) {
                float r0 = 0.f, r1 = 0.f, r2 = 0.f;
                if (valid) {
                    r0 = __fsub_rn(pos[(size_t)nbg * 3 + 0], qx);
                    r1 = __fsub_rn(pos[(size_t)nbg * 3 + 1], qy);
                    r2 = __fsub_rn(pos[(size_t)nbg * 3 + 2], qz);
                }
                uint4 uz = { 0u, 0u, 0u, 0u };
                uint4 ur = { pk2(r0, r1), (u32)f2bf(r2), 0u, 0u };
                *(uint4*)&sA1[k * 104 + 64] = ur;
                *(uint4*)&sA1[k * 104 + 72] = uz;
                *(uint4*)&sA1[k * 104 + 80] = uz;
                *(uint4*)&sA1[k * 104 + 88] = uz;
                *(uint4*)&sA1[k * 104 + 96] = uz;
            }
        }
        __syncthreads();

        // ---- layer 1: A1 x W1t -> H1 (relu) ----
        f32x4 acc1[4];
#pragma unroll
        for (int nt = 0; nt < 4; ++nt) acc1[nt] = f32x4{0.f, 0.f, 0.f, 0.f};
        {
            const int ao = (w * 16 + lr) * 104 + kg * 8;
            const int bo = lr * 104 + kg * 8;
#pragma unroll
            for (int kc = 0; kc < 3; ++kc) {
                s16x8 af = *(const s16x8*)&sA1[ao + kc * 32];
#pragma unroll
                for (int nt = 0; nt < 4; ++nt) {
                    s16x8 bf = *(const s16x8*)&W1t[bo + nt * 1664 + kc * 32];
                    acc1[nt] = mfma16(af, bf, acc1[nt]);
                }
            }
        }
#pragma unroll
        for (int nt = 0; nt < 4; ++nt) {
            const int col = nt * 16 + lr;
#pragma unroll
            for (int r = 0; r < 4; ++r) {
                const int row = w * 16 + kg * 4 + r;
                float v = fmaxf(acc1[nt][r] + bias1[nt], 0.0f);
                sH1[row * 72 + col] = f2bf(v);
            }
        }
        __syncthreads();

        // ---- layer 2: H1 x W2t -> H2 (relu) ----
        f32x4 acc2[4];
#pragma unroll
        for (int nt = 0; nt < 4; ++nt) acc2[nt] = f32x4{0.f, 0.f, 0.f, 0.f};
        {
            const int ao = (w * 16 + lr) * 72 + kg * 8;
            const int bo = lr * 72 + kg * 8;
#pragma unroll
            for (int kc = 0; kc < 2; ++kc) {
                s16x8 af = *(const s16x8*)&sH1[ao + kc * 32];
#pragma unroll
                for (int nt = 0; nt < 4; ++nt) {
                    s16x8 bf = *(const s16x8*)&W2t[bo + nt * 1152 + kc * 32];
                    acc2[nt] = mfma16(af, bf, acc2[nt]);
                }
            }
        }
#pragma unroll
        for (int nt = 0; nt < 4; ++nt) {
            const int col = nt * 16 + lr;
#pragma unroll
            for (int r = 0; r < 4; ++r) {
                const int row = w * 16 + kg * 4 + r;
                float v = fmaxf(acc2[nt][r] + bias2[nt], 0.0f);
                sH2[row * 72 + col] = f2bf(v);
            }
        }
        __syncthreads();

        // ---- layer 3: H2 x W3t ----
        f32x4 acc3[8];
#pragma unroll
        for (int nt = 0; nt < 8; ++nt) acc3[nt] = f32x4{0.f, 0.f, 0.f, 0.f};
        {
            const int ao = (w * 16 + lr) * 72 + kg * 8;
            const int bo = lr * 72 + kg * 8;
#pragma unroll
            for (int kc = 0; kc < 2; ++kc) {
                s16x8 af = *(const s16x8*)&sH2[ao + kc * 32];
#pragma unroll
                for (int nt = 0; nt < 8; ++nt) {
                    s16x8 bf = *(const s16x8*)&W3t[bo + nt * 1152 + kc * 32];
                    acc3[nt] = mfma16(af, bf, acc3[nt]);
                }
            }
        }

        // ---- masked max (bias after max: column-constant) ----
        float pm[8];
#pragma unroll
        for (int nt = 0; nt < 8; ++nt) pm[nt] = -1e30f;
#pragma unroll
        for (int r = 0; r < 4; ++r) {
            const int row = w * 16 + kg * 4 + r;
            if (row < cnt) {
#pragma unroll
                for (int nt = 0; nt < 8; ++nt) pm[nt] = fmaxf(pm[nt], acc3[nt][r]);
            }
        }
#pragma unroll
        for (int nt = 0; nt < 8; ++nt) {
            pm[nt] = fmaxf(pm[nt], __shfl_xor(pm[nt], 16));
            pm[nt] = fmaxf(pm[nt], __shfl_xor(pm[nt], 32));
        }
        __syncthreads();            // cd/ci dead; reuse as f32 partial [4][128]
        float* pbuf = cd;
        if (kg == 0) {
#pragma unroll
            for (int nt = 0; nt < 8; ++nt) pbuf[w * 128 + nt * 16 + lr] = pm[nt];
        }
        __syncthreads();
        if (t < 128) {
            float m = fmaxf(fmaxf(pbuf[t], pbuf[128 + t]),
                            fmaxf(pbuf[256 + t], pbuf[384 + t]));
            out_x[(size_t)c * 128 + t] = m + b3r;
        }
        // loop-top barrier (after slot grab) orders pbuf reads vs next cd write
    }
}

__global__ __launch_bounds__(256) void fused_kernel(
    const float* __restrict__ pos, const float* __restrict__ x,
    const unsigned short* __restrict__ wsW,
    const float* __restrict__ b1, const float* __restrict__ b2,
    const float* __restrict__ b3,
    int* __restrict__ sel, int* __restrict__ wq,
    float* __restrict__ out_x, float* __restrict__ out_pos,
    float* __restrict__ out_batch)
{
    extern __shared__ char smem[];
    if (blockIdx.x < NB) {
        fps_body(smem, pos, sel);
        __syncthreads();            // then join the worker pool (CU was idle)
    }
    worker_loop(smem, pos, x, wsW, b1, b2, b3, sel, wq,
                out_x, out_pos, out_batch);
}

extern "C" void kernel_launch(void* const* d_in, const int* in_sizes, int n_in,
                              void* d_out, int out_size, void* d_ws, size_t ws_size,
                              hipStream_t stream)
{
    const float* x   = (const float*)d_in[0];
    const float* pos = (const float*)d_in[1];
    const float* W1 = (const float*)d_in[3];
    const float* b1 = (const float*)d_in[4];
    const float* W2 = (const float*)d_in[5];
    const float* b2 = (const float*)d_in[6];
    const float* W3 = (const float*)d_in[7];
    const float* b3 = (const float*)d_in[8];

    float* out_x     = (float*)d_out;                    // [8192,128]
    float* out_pos   = out_x + (size_t)MTOT * 128;       // [8192,3]
    float* out_batch = out_pos + (size_t)MTOT * 3;       // [8192]

    int* sel = (int*)d_ws;                               // [8192], -1 = unpublished
    int* wq  = sel + MTOT;                               // [16] (1 used)
    unsigned short* wsW = (unsigned short*)(wq + 16);    // [20480] bf16 weights

    (void)hipFuncSetAttribute((const void*)fused_kernel,
                              hipFuncAttributeMaxDynamicSharedMemorySize, 86016);

    prep_weights<<<113, 256, 0, stream>>>(W1, W2, W3, wsW, sel, wq);
    fused_kernel<<<256, 256, 86016, stream>>>(pos, x, wsW, b1, b2, b3,
                                              sel, wq,
                                              out_x, out_pos, out_batch);
}